// Round 4
// baseline (248.264 us; speedup 1.0000x reference)
//
#include <hip/hip_runtime.h>
#include <hip/hip_bf16.h>

// Difference3DCostVolume: cost[b,c,d,h,w] = l[b,c,h,w] - r[b,c,h,w-d] (w>=d), else 1.0
// Shapes: B=4, C=32, H=96, W=312, D=48. Output [B,C,D,H,W] f32 = 736 MB -> write-bound.
//
// R3 = R2 design (one block per (bc,d); contiguous 119808-B output stream per
// block; linear addressing, no LDS) with the w-tracking bug fixed:
//   w = (4*item) % 312 (float index within row). Init: (4*tid) % 312.
//   Update per grid-stride step: flat += 1024, 1024 mod 312 = 88 ->
//   w += 88; if (w >= 312) w -= 312.  (w < 312 so one subtract suffices.)
// W % 4 == 0 so a float4 never straddles a row; predicate uses w..w+3.

#define BB 4
#define CC 32
#define HH 96
#define WW 312
#define DD 48
#define SLICE (HH * WW)        // 29952 floats = 119808 B
#define ITEMS4 (SLICE / 4)     // 7488 float4 per block
#define NBLOCKS (BB * CC * DD) // 6144
#define WSTEP (1024 % WW)      // 88

// float4 with 4-byte alignment so loads misaligned by d%4 floats are legal.
typedef float float4u __attribute__((ext_vector_type(4), aligned(4)));
typedef float float4a __attribute__((ext_vector_type(4)));

__global__ __launch_bounds__(256) void cost_volume_kernel(
    const float* __restrict__ l, const float* __restrict__ r,
    float* __restrict__ out) {
    const int blk = blockIdx.x;
    const int d = blk % DD;            // uniform per block (SGPR)
    const int bc = blk / DD;
    const int tid = threadIdx.x;

    const float* lbase = l + (size_t)bc * SLICE;
    const float* rbase = r + (size_t)bc * SLICE - d;   // shifted base
    float* obase = out + ((size_t)bc * DD + d) * (size_t)SLICE;

    // Within-row float index for this thread's first item.
    int w = (4 * tid) % WW;            // in {0,4,...,308}

    // ---- Peeled first iteration (item = tid): r offset 4*item-d can be
    // negative only here (4*item < 48 requires tid < 12). Guarded scalar r loads;
    // guard (w>=d) is exactly the validity condition.
    {
        const int item = tid;
        const float4a a = *reinterpret_cast<const float4a*>(lbase + 4 * item);
        float4a v;
        #pragma unroll
        for (int j = 0; j < 4; ++j) {
            v[j] = (w + j >= d) ? (a[j] - rbase[4 * item + j]) : 1.0f;
        }
        *reinterpret_cast<float4a*>(obase + 4 * item) = v;
    }

    // ---- Main loop: pure streaming, r offsets strictly positive (4*item >= 1024 > d).
    for (int item = tid + 256; item < ITEMS4; item += 256) {
        w += WSTEP;
        if (w >= WW) w -= WW;                      // w = (4*item) % WW
        const float4a a = *reinterpret_cast<const float4a*>(lbase + 4 * item);
        const float4u b = *reinterpret_cast<const float4u*>(rbase + 4 * item);
        float4a v;
        v.x = (w     >= d) ? (a.x - b.x) : 1.0f;
        v.y = (w + 1 >= d) ? (a.y - b.y) : 1.0f;
        v.z = (w + 2 >= d) ? (a.z - b.z) : 1.0f;
        v.w = (w + 3 >= d) ? (a.w - b.w) : 1.0f;
        *reinterpret_cast<float4a*>(obase + 4 * item) = v;
    }
}

extern "C" void kernel_launch(void* const* d_in, const int* in_sizes, int n_in,
                              void* d_out, int out_size, void* d_ws, size_t ws_size,
                              hipStream_t stream) {
    const float* l = (const float*)d_in[0];
    const float* r = (const float*)d_in[1];
    float* out = (float*)d_out;
    cost_volume_kernel<<<dim3(NBLOCKS), dim3(256), 0, stream>>>(l, r, out);
}

// Round 5
// 157.904 us; speedup vs baseline: 1.5722x; 1.5722x over previous
//
#include <hip/hip_runtime.h>
#include <hip/hip_bf16.h>

// Difference3DCostVolume: cost[b,c,d,h,w] = l[b,c,h,w] - r[b,c,h,w-d] (w>=d), else 1.0
// Shapes: B=4, C=32, H=96, W=312, D=48. Output [B,C,D,H,W] f32 = 736 MB -> write-bound.
//
// R4 regressed (cache-path reads, misaligned loads). R5 = R1 structure scaled up:
//  - one block per (bc, h-quad): 4 rows, 512 threads, grid 3072.
//  - LDS 25.5 KB -> exactly 4 blocks/CU = 2048 threads (100% occupancy).
//  - l staged as contiguous vec4 (4 adjacent rows = 312 float4, no div).
//  - r staged as 4 byte-rotated copies per row (rsr[hh][rr][m] = row[m-rr]) so the
//    shifted read rs[w-d..w+3-d] is the aligned float4 rsr[hh][d&3][w4-(d>>2)]
//    -> every LDS access is conflict-free ds_read_b128.
//  - stores: per (d), 4 adjacent rows = 4992 B line-aligned whole-line extents.

#define BB 4
#define CC 32
#define HH 96
#define WW 312
#define DD 48
#define HCH 4                    // rows per block
#define NHQ (HH / HCH)           // 24
#define W4 (WW / 4)              // 78
#define RLEN 320                 // padded rotated-row length (>= WW+4, 16B mult)
#define ITEMS (DD * HCH * W4)    // 14976 float4 stores per block
#define NT 512
#define NBLOCKS (BB * CC * NHQ)  // 3072

__global__ __launch_bounds__(NT) void cost_volume_kernel(
    const float* __restrict__ l, const float* __restrict__ r,
    float* __restrict__ out) {
    const int blk = blockIdx.x;
    const int hq = blk % NHQ;
    const int bc = blk / NHQ;
    const int h0 = hq * HCH;
    const int tid = threadIdx.x;

    __shared__ float ls[HCH * WW];        // 4992 B, 4 contiguous l rows
    __shared__ float rsr[HCH][4][RLEN];   // 20480 B, rotated r copies

    const float* lrow = l + ((size_t)bc * HH + h0) * WW;
    const float* rrow = r + ((size_t)bc * HH + h0) * WW;

    // Stage l: 4 adjacent rows are contiguous -> 312 aligned float4, no division.
    for (int i = tid; i < HCH * W4; i += NT)
        reinterpret_cast<float4*>(ls)[i] =
            reinterpret_cast<const float4*>(lrow)[i];

    // Stage 4 byte-rotated copies of each r row (scalar, conflict-free writes).
    for (int i = tid; i < HCH * 4 * RLEN; i += NT) {
        const int hh = i / (4 * RLEN);
        const int rem = i - hh * (4 * RLEN);
        const int rr = rem / RLEN;
        const int m = rem - rr * RLEN;
        const int src = m - rr;
        rsr[hh][rr][m] = (src >= 0 && src < WW) ? rrow[hh * WW + src] : 0.0f;
    }
    __syncthreads();

    // Output base: flat = ((bc*DD + d)*HH + h0 + hh)*WW + w
    float* obase = out + ((size_t)bc * DD * HH + h0) * (size_t)WW;

    for (int item = tid; item < ITEMS; item += NT) {
        const int t2 = item / W4;        // d*4 + hh  (magic-mul div)
        const int w4 = item - t2 * W4;   // 0..77
        const int d = t2 >> 2;
        const int hh = t2 & 3;
        const int q = d >> 2;
        const int rr = d & 3;
        const int k = w4 - q;
        const int kk = (k < 0) ? 0 : k;  // clamped lanes are all-invalid (w+3 < d)
        const int w = w4 * 4;

        const float4 a = *reinterpret_cast<const float4*>(&ls[hh * WW + w]);
        const float4 b = *reinterpret_cast<const float4*>(&rsr[hh][rr][kk * 4]);

        float4 v;
        v.x = (w     >= d) ? (a.x - b.x) : 1.0f;
        v.y = (w + 1 >= d) ? (a.y - b.y) : 1.0f;
        v.z = (w + 2 >= d) ? (a.z - b.z) : 1.0f;
        v.w = (w + 3 >= d) ? (a.w - b.w) : 1.0f;

        *reinterpret_cast<float4*>(obase + ((size_t)d * HH + hh) * WW + w) = v;
    }
}

extern "C" void kernel_launch(void* const* d_in, const int* in_sizes, int n_in,
                              void* d_out, int out_size, void* d_ws, size_t ws_size,
                              hipStream_t stream) {
    const float* l = (const float*)d_in[0];
    const float* r = (const float*)d_in[1];
    float* out = (float*)d_out;
    cost_volume_kernel<<<dim3(NBLOCKS), dim3(NT), 0, stream>>>(l, r, out);
}